// Round 13
// baseline (621.253 us; speedup 1.0000x reference)
//
#include <hip/hip_runtime.h>

using half8  = __attribute__((ext_vector_type(8))) _Float16;
using half4v = __attribute__((ext_vector_type(4))) _Float16;
using f32x4  = __attribute__((ext_vector_type(4))) float;

#define MFMA16(a,b,c) __builtin_amdgcn_mfma_f32_16x16x32_f16((a),(b),(c),0,0,0)
#define LOG2E 1.4426950408889634f
#define KTC  -2.8853900817779268f   /* -2*log2(e): tanh(c) = 2/(1+2^(c*KTC)) - 1 */

__device__ __forceinline__ float sigp_(float zp){           // sigmoid, zp pre-scaled by log2e
  return __builtin_amdgcn_rcpf(1.0f + exp2f(-zp));
}
__device__ __forceinline__ float tanhp_(float zp){          // tanh, zp pre-scaled by log2e
  return fmaf(2.0f, __builtin_amdgcn_rcpf(1.0f + exp2f(-2.0f*zp)), -1.0f);
}
__device__ __forceinline__ float tanhn_(float x){           // tanh, natural units
  return fmaf(2.0f, __builtin_amdgcn_rcpf(1.0f + exp2f(x*KTC)), -1.0f);
}

// ---------------- K0: weight transposes / fp16 packing ----------------
// wkt, wrtb carry a baked log2(e) factor so gates use raw exp2.
// wrtb linear: [4 jt][256 r][256 k], r = 64*gate + i  <-> g = 256*gate + 64*jt + i
__global__ void k0_prep(const float* __restrict__ Wk, const float* __restrict__ Wr,
                        const float* __restrict__ Wd, _Float16* __restrict__ wkt,
                        _Float16* __restrict__ wrtb, _Float16* __restrict__ wdt)
{
  int i = blockIdx.x * 256 + threadIdx.x;
  if (i < 1024*320) {
    int g = i / 320, k = i - g*320;
    wkt[i] = (_Float16)((k < 300) ? Wk[k*1024 + g]*LOG2E : 0.0f);
  }
  if (i < 4*256*256) {
    int jt = i >> 16, r = (i >> 8) & 255, k = i & 255;
    int g = ((r >> 6) << 8) + (jt << 6) + (r & 63);
    wrtb[i] = (_Float16)(Wr[k*1024 + g]*LOG2E);
  }
  if (i < 256*512) {
    int d = i >> 9, k = i & 511;
    wdt[i] = (_Float16)Wd[k*256 + d];
  }
}

// ---------------- K1: embW = (emb @ Wk + b)*log2e -> embw[v][1024] ----------------
__global__ __launch_bounds__(512, 2) void k1_embw(
    const float* __restrict__ emb, const float* __restrict__ bias,
    const _Float16* __restrict__ wkt, _Float16* __restrict__ embw)
{
  __shared__ _Float16 a_s[1024][40];
  __shared__ _Float16 e_s[64][40];
  const int tid = threadIdx.x;
  const int wv = tid >> 6, ln = tid & 63, l16 = ln & 15, lq = ln >> 4;
  const int v0 = blockIdx.x * 64;

  f32x4 acc[8][4];
  #pragma unroll
  for (int ml=0;ml<8;++ml)
    #pragma unroll
    for (int nt=0;nt<4;++nt){ f32x4 z0; z0[0]=0.f;z0[1]=0.f;z0[2]=0.f;z0[3]=0.f; acc[ml][nt]=z0; }

  const int evv = tid >> 2;
  const int ekq = tid & 3;

  for (int c = 0; c < 10; ++c) {
    {
      const uint4* sp  = (const uint4*)(wkt + (size_t)(2*tid)*320 + 32*c);
      uint4 r0=sp[0], r1=sp[1], r2=sp[2], r3=sp[3];
      const uint4* sp2 = (const uint4*)(wkt + (size_t)(2*tid+1)*320 + 32*c);
      uint4 r4=sp2[0], r5=sp2[1], r6=sp2[2], r7=sp2[3];
      uint4* dq  = (uint4*)&a_s[2*tid][0];
      dq[0]=r0; dq[1]=r1; dq[2]=r2; dq[3]=r3;
      uint4* dq2 = (uint4*)&a_s[2*tid+1][0];
      dq2[0]=r4; dq2[1]=r5; dq2[2]=r6; dq2[3]=r7;
    }
    if (tid < 256) {
      int vsrc = v0 + evv; if (vsrc > 19999) vsrc = 19999;
      float f0,f1,f2,f3,f4,f5,f6,f7;
      if (c < 9) {
        const float4* sp = (const float4*)(emb + (size_t)vsrc*300 + 32*c + 8*ekq);
        float4 fa = sp[0], fb = sp[1];
        f0=fa.x; f1=fa.y; f2=fa.z; f3=fa.w; f4=fb.x; f5=fb.y; f6=fb.z; f7=fb.w;
      } else {
        const float* sp = emb + (size_t)vsrc*300;
        int k0 = 288 + 8*ekq;
        f0 = (k0+0<300)? sp[k0+0] : 0.f;  f1 = (k0+1<300)? sp[k0+1] : 0.f;
        f2 = (k0+2<300)? sp[k0+2] : 0.f;  f3 = (k0+3<300)? sp[k0+3] : 0.f;
        f4 = (k0+4<300)? sp[k0+4] : 0.f;  f5 = (k0+5<300)? sp[k0+5] : 0.f;
        f6 = (k0+6<300)? sp[k0+6] : 0.f;  f7 = (k0+7<300)? sp[k0+7] : 0.f;
      }
      half8 hv;
      hv[0]=(_Float16)f0; hv[1]=(_Float16)f1; hv[2]=(_Float16)f2; hv[3]=(_Float16)f3;
      hv[4]=(_Float16)f4; hv[5]=(_Float16)f5; hv[6]=(_Float16)f6; hv[7]=(_Float16)f7;
      *(half8*)&e_s[evv][8*ekq] = hv;
    }
    __syncthreads();
    half8 bf[4];
    #pragma unroll
    for (int nt=0;nt<4;++nt) bf[nt] = *(const half8*)&e_s[16*nt + l16][8*lq];
    #pragma unroll
    for (int ml=0;ml<8;++ml) {
      half8 af = *(const half8*)&a_s[16*(8*wv+ml) + l16][8*lq];
      #pragma unroll
      for (int nt=0;nt<4;++nt) acc[ml][nt] = MFMA16(af, bf[nt], acc[ml][nt]);
    }
    __syncthreads();
  }
  #pragma unroll
  for (int ml=0;ml<8;++ml) {
    int g0 = 16*(8*wv+ml) + 4*lq;
    float4 bv = *(const float4*)&bias[g0];
    float bvr[4] = {bv.x*LOG2E, bv.y*LOG2E, bv.z*LOG2E, bv.w*LOG2E};
    int jt = (g0 >> 6) & 3;
    int c0 = ((g0 >> 8) << 6) + (g0 & 63);
    #pragma unroll
    for (int nt=0;nt<4;++nt) {
      int v = v0 + 16*nt + l16;
      if (v < 20000) {
        half4v hv;
        hv[0]=(_Float16)(acc[ml][nt][0]+bvr[0]);
        hv[1]=(_Float16)(acc[ml][nt][1]+bvr[1]);
        hv[2]=(_Float16)(acc[ml][nt][2]+bvr[2]);
        hv[3]=(_Float16)(acc[ml][nt][3]+bvr[3]);
        *(half4v*)&embw[(size_t)v*1024 + 256*jt + c0] = hv;
      }
    }
  }
}

// ---------------- K2: bi-LSTM recurrence, 1 block = (card, direction) ----------------
// R13 changes (vs R12): (1) x token table staged to LDS once (kills the per-step
// x-load -> gather serial chain); (2) eR gather double-buffered with STATIC names
// (eRa even jt / eRb odd jt) and ISSUE_E placed BEFORE the ACC wait -> a full jt body
// (~1-1.5K cyc) of gather lead instead of ~0-600 (R6-R12's invariant ~545us floor was
// this lead); (3) jt loop unrolled x2 so parity is compile-time; __launch_bounds__
// (256,1) -> ~250-reg demand allocates spill-free, and at <=256 total the HW still
// co-schedules 2 blocks/CU (2x250 <= 512 pool). Tell: OccupancyPercent ~23% good,
// ~12% means allocator exceeded 256.

#define ISSUE_E(ER, JT, TT) do { \
    _Pragma("unroll") for (int nt=0;nt<3;++nt) { \
      int idx_ = x_lds[pA12[nt] + (TT)]; \
      const _Float16* ep = embw + (size_t)idx_*1024 + 256*(JT) + ebase; \
      _Pragma("unroll") for (int g=0;g<4;++g) ER[g][nt] = *(const half4v*)(ep + 64*g); \
    } } while(0)

#define ACC_FROM_E(ER) do { \
    _Pragma("unroll") for (int g=0;g<4;++g) \
      _Pragma("unroll") for (int nt=0;nt<3;++nt) { \
        f32x4 a0; a0[0]=(float)ER[g][nt][0]; a0[1]=(float)ER[g][nt][1]; \
        a0[2]=(float)ER[g][nt][2]; a0[3]=(float)ER[g][nt][3]; acc[g][nt]=a0; \
      } } while(0)

#define ISSUE_A(BUF,JT,KQ) do { \
    const _Float16* ap = wrtb + abase + 65536*(JT) + 64*(KQ); \
    _Pragma("unroll") for (int g=0;g<4;++g) { \
      BUF[2*g+0] = *(const half8*)(ap + 16384*g); \
      BUF[2*g+1] = *(const half8*)(ap + 16384*g + 32); \
    } } while(0)

#define MFMAQ(BUF,KQ) do { \
    _Pragma("unroll") for (int kk2=0;kk2<2;++kk2) { \
      half8 bF[3]; \
      _Pragma("unroll") for (int nt=0;nt<3;++nt) \
        bF[nt] = *(const half8*)(hc + bbase[nt] + ((64*(KQ)+32*kk2+8*lq) ^ bswz[nt])); \
      _Pragma("unroll") for (int g=0;g<4;++g) \
        _Pragma("unroll") for (int nt=0;nt<3;++nt) \
          acc[g][nt] = MFMA16(BUF[2*g+kk2], bF[nt], acc[g][nt]); \
    } } while(0)

#define GATES_J(JT, CR) do { \
    _Pragma("unroll") for (int nt=0;nt<3;++nt) { \
      f32x4 cn_; half4v hv; \
      _Pragma("unroll") for (int r=0;r<4;++r) { \
        float zi=acc[0][nt][r], zf=acc[1][nt][r], zg=acc[2][nt][r], zo=acc[3][nt][r]; \
        float cn = fmaf(sigp_(zf), CR[nt][r], sigp_(zi)*tanhp_(zg)); \
        cn_[r]=cn; hv[r]=(_Float16)(sigp_(zo)*tanhn_(cn)); \
      } \
      CR[nt] = cn_; \
      *(half4v*)(hn + bbase[nt] + ((64*(JT)+16*hq+4*lq) ^ bswz[nt])) = hv; \
    } } while(0)

#define GATES0_J(JT, CR) do { \
    _Pragma("unroll") for (int nt=0;nt<3;++nt) { \
      f32x4 cn_; half4v hv; \
      _Pragma("unroll") for (int r=0;r<4;++r) { \
        float zi=acc[0][nt][r], zg=acc[2][nt][r], zo=acc[3][nt][r]; \
        float cn = sigp_(zi)*tanhp_(zg); \
        cn_[r]=cn; hv[r]=(_Float16)(sigp_(zo)*tanhn_(cn)); \
      } \
      CR[nt] = cn_; \
      *(half4v*)(hn + bbase[nt] + ((64*(JT)+16*hq+4*lq) ^ bswz[nt])) = hv; \
    } } while(0)

__global__ __launch_bounds__(256, 1) void k2_rnn(
    const int* __restrict__ x, const _Float16* __restrict__ embw,
    const _Float16* __restrict__ wrtb, _Float16* __restrict__ hstate)
{
  __shared__ _Float16 h_s[2][48][256];   // 48 KB
  __shared__ int x_lds[480];             // token table for this card (1.9 KB)

  const int bid = blockIdx.x;
  const int b   = bid & 255;             // card
  const int dir = bid >> 8;              // 0 = fw, 1 = bw (block-uniform)
  const int tid = threadIdx.x;
  const int wv  = tid >> 6;
  const int ln  = tid & 63;
  const int l16 = ln & 15;
  const int lq  = ln >> 4;
  const int hq  = wv;                    // 16-col subtile in each 64-col gate chunk

  const int dtt0 = dir ? 11 : 0;
  const int dsgn = dir ? -1 : 1;
  const int xb   = b*480;

  if (tid < 240) {                       // stage token table to LDS
    *(int2*)&x_lds[2*tid] = *(const int2*)(x + xb + 2*tid);
  }

  int pA12[3], bbase[3], bswz[3];
  #pragma unroll
  for (int nt=0;nt<3;++nt) {
    int s = 16*nt + l16;                 // seq row 0..47 (40..47 dup path 39)
    pA12[nt] = ((s < 40) ? s : 39) * 12;
    bbase[nt] = s*256; bswz[nt] = (s&7)<<3;
  }
  const int ebase = 16*hq + 4*lq;
  const size_t abase = (size_t)(16*hq + l16)*256 + 8*lq;

  half4v eRa[4][3], eRb[4][3];
  half8  aRa[8], aRb[8];
  f32x4  acc[4][3];
  f32x4  cA[3], cB[3], cC[3], cD[3];     // cell state, statically-named per jt chunk

  __syncthreads();                       // x_lds ready

  // ---- t = 0: z = xg (h=0, no MFMA; c starts at 0); eRa/eRb alternation primed ----
  {
    _Float16* hn = &h_s[1][0][0];
    ISSUE_E(eRa, 0, dtt0);
    ACC_FROM_E(eRa); ISSUE_E(eRb, 1, dtt0);        GATES0_J(0, cA);
    ACC_FROM_E(eRb); ISSUE_E(eRa, 2, dtt0);        GATES0_J(1, cB);
    ACC_FROM_E(eRa); ISSUE_E(eRb, 3, dtt0);        GATES0_J(2, cC);
    ACC_FROM_E(eRb); ISSUE_E(eRa, 0, dtt0 + dsgn); GATES0_J(3, cD);
  }

  // ---- t = 1..11: 4 jt chunks/step; eR gathers issued a full jt body ahead ----
  #pragma unroll 1
  for (int t = 1; t < 12; ++t) {
    __syncthreads();                     // h[t&1] committed by all waves
    const _Float16* hc = &h_s[t&1][0][0];
    _Float16*       hn = &h_s[(t+1)&1][0][0];
    const bool last = (t == 11);
    const int ttc = dtt0 + dsgn*t;
    #pragma unroll 1
    for (int jth = 0; jth < 2; ++jth) {
      { // even jt = 2*jth: consume eRa, prefetch chunk jt+1 -> eRb (BEFORE acc wait)
        const int jt_ = 2*jth;
        ISSUE_A(aRa, jt_, 0);
        ISSUE_A(aRb, jt_, 1);
        ISSUE_E(eRb, jt_+1, ttc);
        ACC_FROM_E(eRa);
        MFMAQ(aRa, 0); ISSUE_A(aRa, jt_, 2);
        MFMAQ(aRb, 1); ISSUE_A(aRb, jt_, 3);
        MFMAQ(aRa, 2);
        MFMAQ(aRb, 3);
        if (jth == 0) { GATES_J(0, cA); } else { GATES_J(2, cC); }
      }
      { // odd jt = 2*jth+1: consume eRb, prefetch -> eRa
        const int jt_ = 2*jth + 1;
        ISSUE_A(aRa, jt_, 0);
        ISSUE_A(aRb, jt_, 1);
        if (jth == 0)   { ISSUE_E(eRa, 2, ttc); }
        else if (!last) { ISSUE_E(eRa, 0, ttc + dsgn); }
        ACC_FROM_E(eRb);
        MFMAQ(aRa, 0); ISSUE_A(aRa, jt_, 2);
        MFMAQ(aRb, 1); ISSUE_A(aRb, jt_, 3);
        MFMAQ(aRa, 2);
        MFMAQ(aRb, 3);
        if (jth == 0) { GATES_J(1, cB); } else { GATES_J(3, cD); }
      }
    }
  }
  __syncthreads();                       // final state (h_s[0]) committed

  // ---- export final h (unswizzled) to hstate[b][dir][40][256] ----
  #pragma unroll
  for (int pass = 0; pass < 5; ++pass) {
    int row = 8*pass + (tid >> 5);
    int c0  = (tid & 31) * 8;
    half8 v = *(const half8*)&h_s[0][row][c0 ^ ((row & 7) << 3)];
    *(half8*)&hstate[(((size_t)b*2 + dir)*40 + row)*256 + c0] = v;
  }
}

// ---------------- K3: dense + attention head, 1 block = 1 card ----------------
__global__ __launch_bounds__(256) void k3_head(
    const float* __restrict__ bd, const float* __restrict__ att,
    const _Float16* __restrict__ hstate, const _Float16* __restrict__ wdt,
    float* __restrict__ out)
{
  __shared__ _Float16 d_s[256][56];
  __shared__ float att_s[256];
  __shared__ float sc_s[40];
  __shared__ float wgt[40];

  const int b   = blockIdx.x;
  const int tid = threadIdx.x;
  const int wv  = tid >> 6;
  const int ln  = tid & 63;
  const int l16 = ln & 15;
  const int lq  = ln >> 4;

  att_s[tid] = att[tid];

  int pD2[3];
  #pragma unroll
  for (int nt=0;nt<3;++nt){ int p = 16*nt + l16; pD2[nt] = (p < 40) ? p : 39; }
  const _Float16* hb = hstate + (size_t)b*2*40*256;

  f32x4 dacc[4][3];
  #pragma unroll
  for (int ml=0;ml<4;++ml)
    #pragma unroll
    for (int nt=0;nt<3;++nt){ f32x4 z0; z0[0]=0.f;z0[1]=0.f;z0[2]=0.f;z0[3]=0.f; dacc[ml][nt]=z0; }

  #pragma unroll
  for (int kq = 0; kq < 8; ++kq) {        // k slices of 64: 0..3 fw state, 4..7 bw state
    half8 adA[4], adB[4];
    #pragma unroll
    for (int ml=0;ml<4;++ml) {
      const _Float16* wp = wdt + (size_t)(16*(4*wv+ml)+l16)*512 + 64*kq + 8*lq;
      adA[ml] = *(const half8*)(wp);
      adB[ml] = *(const half8*)(wp + 32);
    }
    #pragma unroll
    for (int kk2=0;kk2<2;++kk2) {
      half8 bD[3];
      #pragma unroll
      for (int nt=0;nt<3;++nt)
        bD[nt] = *(const half8*)(hb + ((size_t)(kq>>2)*40 + pD2[nt])*256
                                    + 64*(kq&3) + 32*kk2 + 8*lq);
      #pragma unroll
      for (int ml=0;ml<4;++ml) {
        half8 a0 = kk2 ? adB[ml] : adA[ml];
        #pragma unroll
        for (int nt=0;nt<3;++nt) dacc[ml][nt] = MFMA16(a0, bD[nt], dacc[ml][nt]);
      }
    }
  }
  #pragma unroll
  for (int ml = 0; ml < 4; ++ml) {
    int d0 = 16*(4*wv+ml) + 4*lq;
    float4 bv = *(const float4*)&bd[d0];
    float bvr[4] = {bv.x, bv.y, bv.z, bv.w};
    #pragma unroll
    for (int nt = 0; nt < 3; ++nt) {
      int p = 16*nt + l16;
      #pragma unroll
      for (int r = 0; r < 4; ++r) {
        float val = tanhn_(dacc[ml][nt][r] + bvr[r]);
        d_s[d0 + r][p] = (_Float16)val;
      }
    }
  }
  __syncthreads();
  // ---------- attention: 10 path-scores per wave, softmax, weighted sum ----------
  #pragma unroll
  for (int q = 0; q < 10; ++q) {
    int pp = 10*wv + q;
    float s = 0.0f;
    #pragma unroll
    for (int j = 0; j < 4; ++j) {
      int d = 64*j + ln;
      s += (float)d_s[d][pp] * att_s[d];
    }
    #pragma unroll
    for (int off = 32; off > 0; off >>= 1) s += __shfl_xor(s, off);
    if (ln == 0) sc_s[pp] = s;
  }
  __syncthreads();
  if (wv == 0) {
    float sc = (ln < 40) ? sc_s[ln] : -1e30f;
    float m = sc;
    #pragma unroll
    for (int off = 32; off > 0; off >>= 1) m = fmaxf(m, __shfl_xor(m, off));
    float e = __expf(sc - m);
    float se = e;
    #pragma unroll
    for (int off = 32; off > 0; off >>= 1) se += __shfl_xor(se, off);
    if (ln < 40) wgt[ln] = e / se;
  }
  __syncthreads();
  {
    float o = 0.0f;
    #pragma unroll 8
    for (int p = 0; p < 40; ++p) o += wgt[p] * (float)d_s[tid][p];
    out[b*256 + tid] = o;
  }
}

extern "C" void kernel_launch(void* const* d_in, const int* in_sizes, int n_in,
                              void* d_out, int out_size, void* d_ws, size_t ws_size,
                              hipStream_t stream)
{
  (void)in_sizes; (void)n_in; (void)out_size;
  const int*   x   = (const int*)  d_in[0];
  const float* emb = (const float*)d_in[1];
  const float* Wk  = (const float*)d_in[2];
  const float* Wr  = (const float*)d_in[3];
  const float* bi  = (const float*)d_in[4];
  const float* Wd  = (const float*)d_in[5];
  const float* bd  = (const float*)d_in[6];
  const float* att = (const float*)d_in[7];
  float* out = (float*)d_out;

  if (ws_size < 52887552u) return;   // need 52.9 MB scratch
  char* ws = (char*)d_ws;
  _Float16* embw   = (_Float16*)(ws + 0);          // [20000][1024] fp16 = 40,960,000 B
  _Float16* wrtb   = (_Float16*)(ws + 40960000);   // [4][256][256] fp16 =    524,288 B
  _Float16* wkt    = (_Float16*)(ws + 41484288);   // [1024][320]   fp16 =    655,360 B
  _Float16* wdt    = (_Float16*)(ws + 42139648);   // [256][512]    fp16 =    262,144 B
  _Float16* hstate = (_Float16*)(ws + 42401792);   // [256][2][40][256] fp16 = 10,485,760 B

  k0_prep<<<dim3(1280), dim3(256), 0, stream>>>(Wk, Wr, Wd, wkt, wrtb, wdt);
  k1_embw<<<dim3(313), dim3(512), 0, stream>>>(emb, bi, wkt, embw);
  k2_rnn <<<dim3(512), dim3(256), 0, stream>>>(x, embw, wrtb, hstate);
  k3_head<<<dim3(256), dim3(256), 0, stream>>>(bd, att, hstate, wdt, out);
}

// Round 14
// 508.932 us; speedup vs baseline: 1.2207x; 1.2207x over previous
//
#include <hip/hip_runtime.h>

using half8  = __attribute__((ext_vector_type(8))) _Float16;
using half4v = __attribute__((ext_vector_type(4))) _Float16;
using f32x4  = __attribute__((ext_vector_type(4))) float;

#define MFMA16(a,b,c) __builtin_amdgcn_mfma_f32_16x16x32_f16((a),(b),(c),0,0,0)
#define LOG2E 1.4426950408889634f
#define KTC  -2.8853900817779268f   /* -2*log2(e): tanh(c) = 2/(1+2^(c*KTC)) - 1 */

__device__ __forceinline__ float sigp_(float zp){           // sigmoid, zp pre-scaled by log2e
  return __builtin_amdgcn_rcpf(1.0f + exp2f(-zp));
}
__device__ __forceinline__ float tanhp_(float zp){          // tanh, zp pre-scaled by log2e
  return fmaf(2.0f, __builtin_amdgcn_rcpf(1.0f + exp2f(-2.0f*zp)), -1.0f);
}
__device__ __forceinline__ float tanhn_(float x){           // tanh, natural units
  return fmaf(2.0f, __builtin_amdgcn_rcpf(1.0f + exp2f(x*KTC)), -1.0f);
}

// ---------------- K0: weight transposes / fp16 packing ----------------
// R14: wrtb is FRAGMENT-MAJOR: [jt][kq][g][kk2][hq][lane 0..63][8 fp16] so a wave's
// MFMA A-fragment load is 64 lanes x 16B fully contiguous (1KB streaming) instead of
// 16 rows scattered 512B apart. Same values as R13's linear layout, just permuted.
// Element (jt,kq,g,kk2,hq,ln,b): k = kq*64+kk2*32+(ln>>4)*8+b,
//                                G = g*256+jt*64+hq*16+(ln&15); val = Wr[k][G]*log2e.
__global__ void k0_prep(const float* __restrict__ Wk, const float* __restrict__ Wr,
                        const float* __restrict__ Wd, _Float16* __restrict__ wkt,
                        _Float16* __restrict__ wrtb, _Float16* __restrict__ wdt)
{
  int i = blockIdx.x * 256 + threadIdx.x;
  if (i < 1024*320) {
    int g = i / 320, k = i - g*320;
    wkt[i] = (_Float16)((k < 300) ? Wk[k*1024 + g]*LOG2E : 0.0f);
  }
  if (i < 4*256*256) {
    int b   = i & 7;
    int ln2 = (i >> 3) & 63;
    int hq2 = (i >> 9) & 3;
    int kk2 = (i >> 11) & 1;
    int g   = (i >> 12) & 3;
    int kq  = (i >> 14) & 3;
    int jt  = (i >> 16) & 3;
    int k = kq*64 + kk2*32 + (ln2 >> 4)*8 + b;
    int G = g*256 + jt*64 + hq2*16 + (ln2 & 15);
    wrtb[i] = (_Float16)(Wr[k*1024 + G]*LOG2E);
  }
  if (i < 256*512) {
    int d = i >> 9, k = i & 511;
    wdt[i] = (_Float16)Wd[k*256 + d];
  }
}

// ---------------- K1: embW = (emb @ Wk + b)*log2e ----------------
// R14: embw per-row layout is fragment-major: [v][jt][hq][lq][g][4] so one lane's
// acc-init for ALL 4 gates at its (hq,lq) is 32B contiguous (2 x 16B loads vs
// R13's 4 x 8B scattered). Values unchanged.
__global__ __launch_bounds__(512, 2) void k1_embw(
    const float* __restrict__ emb, const float* __restrict__ bias,
    const _Float16* __restrict__ wkt, _Float16* __restrict__ embw)
{
  __shared__ _Float16 a_s[1024][40];
  __shared__ _Float16 e_s[64][40];
  const int tid = threadIdx.x;
  const int wv = tid >> 6, ln = tid & 63, l16 = ln & 15, lq = ln >> 4;
  const int v0 = blockIdx.x * 64;

  f32x4 acc[8][4];
  #pragma unroll
  for (int ml=0;ml<8;++ml)
    #pragma unroll
    for (int nt=0;nt<4;++nt){ f32x4 z0; z0[0]=0.f;z0[1]=0.f;z0[2]=0.f;z0[3]=0.f; acc[ml][nt]=z0; }

  const int evv = tid >> 2;
  const int ekq = tid & 3;

  for (int c = 0; c < 10; ++c) {
    {
      const uint4* sp  = (const uint4*)(wkt + (size_t)(2*tid)*320 + 32*c);
      uint4 r0=sp[0], r1=sp[1], r2=sp[2], r3=sp[3];
      const uint4* sp2 = (const uint4*)(wkt + (size_t)(2*tid+1)*320 + 32*c);
      uint4 r4=sp2[0], r5=sp2[1], r6=sp2[2], r7=sp2[3];
      uint4* dq  = (uint4*)&a_s[2*tid][0];
      dq[0]=r0; dq[1]=r1; dq[2]=r2; dq[3]=r3;
      uint4* dq2 = (uint4*)&a_s[2*tid+1][0];
      dq2[0]=r4; dq2[1]=r5; dq2[2]=r6; dq2[3]=r7;
    }
    if (tid < 256) {
      int vsrc = v0 + evv; if (vsrc > 19999) vsrc = 19999;
      float f0,f1,f2,f3,f4,f5,f6,f7;
      if (c < 9) {
        const float4* sp = (const float4*)(emb + (size_t)vsrc*300 + 32*c + 8*ekq);
        float4 fa = sp[0], fb = sp[1];
        f0=fa.x; f1=fa.y; f2=fa.z; f3=fa.w; f4=fb.x; f5=fb.y; f6=fb.z; f7=fb.w;
      } else {
        const float* sp = emb + (size_t)vsrc*300;
        int k0 = 288 + 8*ekq;
        f0 = (k0+0<300)? sp[k0+0] : 0.f;  f1 = (k0+1<300)? sp[k0+1] : 0.f;
        f2 = (k0+2<300)? sp[k0+2] : 0.f;  f3 = (k0+3<300)? sp[k0+3] : 0.f;
        f4 = (k0+4<300)? sp[k0+4] : 0.f;  f5 = (k0+5<300)? sp[k0+5] : 0.f;
        f6 = (k0+6<300)? sp[k0+6] : 0.f;  f7 = (k0+7<300)? sp[k0+7] : 0.f;
      }
      half8 hv;
      hv[0]=(_Float16)f0; hv[1]=(_Float16)f1; hv[2]=(_Float16)f2; hv[3]=(_Float16)f3;
      hv[4]=(_Float16)f4; hv[5]=(_Float16)f5; hv[6]=(_Float16)f6; hv[7]=(_Float16)f7;
      *(half8*)&e_s[evv][8*ekq] = hv;
    }
    __syncthreads();
    half8 bf[4];
    #pragma unroll
    for (int nt=0;nt<4;++nt) bf[nt] = *(const half8*)&e_s[16*nt + l16][8*lq];
    #pragma unroll
    for (int ml=0;ml<8;++ml) {
      half8 af = *(const half8*)&a_s[16*(8*wv+ml) + l16][8*lq];
      #pragma unroll
      for (int nt=0;nt<4;++nt) acc[ml][nt] = MFMA16(af, bf[nt], acc[ml][nt]);
    }
    __syncthreads();
  }
  #pragma unroll
  for (int ml=0;ml<8;++ml) {
    int g0 = 16*(8*wv+ml) + 4*lq;
    float4 bv = *(const float4*)&bias[g0];
    float bvr[4] = {bv.x*LOG2E, bv.y*LOG2E, bv.z*LOG2E, bv.w*LOG2E};
    int jt  = (g0 >> 6) & 3;
    int coff = ((g0 >> 4) & 3)*64 + ((g0 >> 2) & 3)*16 + (g0 >> 8)*4;  // hq*64+lq*16+gate*4
    #pragma unroll
    for (int nt=0;nt<4;++nt) {
      int v = v0 + 16*nt + l16;
      if (v < 20000) {
        half4v hv;
        hv[0]=(_Float16)(acc[ml][nt][0]+bvr[0]);
        hv[1]=(_Float16)(acc[ml][nt][1]+bvr[1]);
        hv[2]=(_Float16)(acc[ml][nt][2]+bvr[2]);
        hv[3]=(_Float16)(acc[ml][nt][3]+bvr[3]);
        *(half4v*)&embw[(size_t)v*1024 + 256*jt + coff] = hv;
      }
    }
  }
}

// ---------------- K2: bi-LSTM recurrence, 1 block = (card, direction) ----------------
// R14 (vs R13): ALL global A/E loads are now lane-contiguous thanks to the k0/k1
// fragment-major repack. R11-R13 proved the kernel is bound by a saturated per-CU
// memory pipe (2x occupancy -> same time, same issue rates); per wave-step the OLD
// layout issued ~2.8K scattered line-transactions (~4.5cyc each). New: ISSUE_A = 8x
// fully-coalesced 1KB streams, ISSUE_E = 6x 16B-contiguous gathers (was 12x 8B).
// Math/fragments identical (verified absmax 3.05e-5 lineage).

#define ISSUE_E(ER, JT, TT) do { \
    _Pragma("unroll") for (int nt=0;nt<3;++nt) { \
      int idx_ = x_lds[pA12[nt] + (TT)]; \
      const _Float16* ep = embw + (size_t)idx_*1024 + (JT)*256 + ebase; \
      ER[0][nt] = *(const half8*)(ep); \
      ER[1][nt] = *(const half8*)(ep + 8); \
    } } while(0)

#define ACC_FROM_E(ER) do { \
    _Pragma("unroll") for (int g=0;g<4;++g) \
      _Pragma("unroll") for (int nt=0;nt<3;++nt) { \
        f32x4 a0; \
        a0[0]=(float)ER[g>>1][nt][(g&1)*4+0]; a0[1]=(float)ER[g>>1][nt][(g&1)*4+1]; \
        a0[2]=(float)ER[g>>1][nt][(g&1)*4+2]; a0[3]=(float)ER[g>>1][nt][(g&1)*4+3]; \
        acc[g][nt]=a0; \
      } } while(0)

#define ISSUE_A(BUF,JT,KQ) do { \
    const _Float16* ap = wrtb + (size_t)((JT)*4+(KQ))*16384 + abase; \
    _Pragma("unroll") for (int g=0;g<4;++g) { \
      BUF[2*g+0] = *(const half8*)(ap + (2*g+0)*2048); \
      BUF[2*g+1] = *(const half8*)(ap + (2*g+1)*2048); \
    } } while(0)

#define MFMAQ(BUF,KQ) do { \
    _Pragma("unroll") for (int kk2=0;kk2<2;++kk2) { \
      half8 bF[3]; \
      _Pragma("unroll") for (int nt=0;nt<3;++nt) \
        bF[nt] = *(const half8*)(hc + bbase[nt] + ((64*(KQ)+32*kk2+8*lq) ^ bswz[nt])); \
      _Pragma("unroll") for (int g=0;g<4;++g) \
        _Pragma("unroll") for (int nt=0;nt<3;++nt) \
          acc[g][nt] = MFMA16(BUF[2*g+kk2], bF[nt], acc[g][nt]); \
    } } while(0)

#define GATES_J(JT, CR) do { \
    _Pragma("unroll") for (int nt=0;nt<3;++nt) { \
      f32x4 cn_; half4v hv; \
      _Pragma("unroll") for (int r=0;r<4;++r) { \
        float zi=acc[0][nt][r], zf=acc[1][nt][r], zg=acc[2][nt][r], zo=acc[3][nt][r]; \
        float cn = fmaf(sigp_(zf), CR[nt][r], sigp_(zi)*tanhp_(zg)); \
        cn_[r]=cn; hv[r]=(_Float16)(sigp_(zo)*tanhn_(cn)); \
      } \
      CR[nt] = cn_; \
      *(half4v*)(hn + bbase[nt] + ((64*(JT)+16*hq+4*lq) ^ bswz[nt])) = hv; \
    } } while(0)

#define GATES0_J(JT, CR) do { \
    _Pragma("unroll") for (int nt=0;nt<3;++nt) { \
      f32x4 cn_; half4v hv; \
      _Pragma("unroll") for (int r=0;r<4;++r) { \
        float zi=acc[0][nt][r], zg=acc[2][nt][r], zo=acc[3][nt][r]; \
        float cn = sigp_(zi)*tanhp_(zg); \
        cn_[r]=cn; hv[r]=(_Float16)(sigp_(zo)*tanhn_(cn)); \
      } \
      CR[nt] = cn_; \
      *(half4v*)(hn + bbase[nt] + ((64*(JT)+16*hq+4*lq) ^ bswz[nt])) = hv; \
    } } while(0)

__global__ __launch_bounds__(256, 1) void k2_rnn(
    const int* __restrict__ x, const _Float16* __restrict__ embw,
    const _Float16* __restrict__ wrtb, _Float16* __restrict__ hstate)
{
  __shared__ _Float16 h_s[2][48][256];   // 48 KB
  __shared__ int x_lds[480];             // token table for this card (1.9 KB)

  const int bid = blockIdx.x;
  const int b   = bid & 255;             // card
  const int dir = bid >> 8;              // 0 = fw, 1 = bw (block-uniform)
  const int tid = threadIdx.x;
  const int wv  = tid >> 6;
  const int ln  = tid & 63;
  const int l16 = ln & 15;
  const int lq  = ln >> 4;
  const int hq  = wv;                    // 16-col subtile in each 64-col gate chunk

  const int dtt0 = dir ? 11 : 0;
  const int dsgn = dir ? -1 : 1;
  const int xb   = b*480;

  if (tid < 240) {                       // stage token table to LDS
    *(int2*)&x_lds[2*tid] = *(const int2*)(x + xb + 2*tid);
  }

  int pA12[3], bbase[3], bswz[3];
  #pragma unroll
  for (int nt=0;nt<3;++nt) {
    int s = 16*nt + l16;                 // seq row 0..47 (40..47 dup path 39)
    pA12[nt] = ((s < 40) ? s : 39) * 12;
    bbase[nt] = s*256; bswz[nt] = (s&7)<<3;
  }
  const int ebase = hq*64 + lq*16;       // fragment-major embw offset within [v][jt]
  const size_t abase = (size_t)hq*512 + ln*8;  // fragment-major wrtb: lane-contiguous

  half8 eRa[2][3], eRb[2][3];
  half8  aRa[8], aRb[8];
  f32x4  acc[4][3];
  f32x4  cA[3], cB[3], cC[3], cD[3];     // cell state, statically-named per jt chunk

  __syncthreads();                       // x_lds ready

  // ---- t = 0: z = xg (h=0, no MFMA; c starts at 0); eRa/eRb alternation primed ----
  {
    _Float16* hn = &h_s[1][0][0];
    ISSUE_E(eRa, 0, dtt0);
    ACC_FROM_E(eRa); ISSUE_E(eRb, 1, dtt0);        GATES0_J(0, cA);
    ACC_FROM_E(eRb); ISSUE_E(eRa, 2, dtt0);        GATES0_J(1, cB);
    ACC_FROM_E(eRa); ISSUE_E(eRb, 3, dtt0);        GATES0_J(2, cC);
    ACC_FROM_E(eRb); ISSUE_E(eRa, 0, dtt0 + dsgn); GATES0_J(3, cD);
  }

  // ---- t = 1..11: 4 jt chunks/step; eR gathers issued a full jt body ahead ----
  #pragma unroll 1
  for (int t = 1; t < 12; ++t) {
    __syncthreads();                     // h[t&1] committed by all waves
    const _Float16* hc = &h_s[t&1][0][0];
    _Float16*       hn = &h_s[(t+1)&1][0][0];
    const bool last = (t == 11);
    const int ttc = dtt0 + dsgn*t;
    #pragma unroll 1
    for (int jth = 0; jth < 2; ++jth) {
      { // even jt = 2*jth: consume eRa, prefetch chunk jt+1 -> eRb (BEFORE acc wait)
        const int jt_ = 2*jth;
        ISSUE_A(aRa, jt_, 0);
        ISSUE_A(aRb, jt_, 1);
        ISSUE_E(eRb, jt_+1, ttc);
        ACC_FROM_E(eRa);
        MFMAQ(aRa, 0); ISSUE_A(aRa, jt_, 2);
        MFMAQ(aRb, 1); ISSUE_A(aRb, jt_, 3);
        MFMAQ(aRa, 2);
        MFMAQ(aRb, 3);
        if (jth == 0) { GATES_J(0, cA); } else { GATES_J(2, cC); }
      }
      { // odd jt = 2*jth+1: consume eRb, prefetch -> eRa
        const int jt_ = 2*jth + 1;
        ISSUE_A(aRa, jt_, 0);
        ISSUE_A(aRb, jt_, 1);
        if (jth == 0)   { ISSUE_E(eRa, 2, ttc); }
        else if (!last) { ISSUE_E(eRa, 0, ttc + dsgn); }
        ACC_FROM_E(eRb);
        MFMAQ(aRa, 0); ISSUE_A(aRa, jt_, 2);
        MFMAQ(aRb, 1); ISSUE_A(aRb, jt_, 3);
        MFMAQ(aRa, 2);
        MFMAQ(aRb, 3);
        if (jth == 0) { GATES_J(1, cB); } else { GATES_J(3, cD); }
      }
    }
  }
  __syncthreads();                       // final state (h_s[0]) committed

  // ---- export final h (unswizzled) to hstate[b][dir][40][256] ----
  #pragma unroll
  for (int pass = 0; pass < 5; ++pass) {
    int row = 8*pass + (tid >> 5);
    int c0  = (tid & 31) * 8;
    half8 v = *(const half8*)&h_s[0][row][c0 ^ ((row & 7) << 3)];
    *(half8*)&hstate[(((size_t)b*2 + dir)*40 + row)*256 + c0] = v;
  }
}

// ---------------- K3: dense + attention head, 1 block = 1 card ----------------
__global__ __launch_bounds__(256) void k3_head(
    const float* __restrict__ bd, const float* __restrict__ att,
    const _Float16* __restrict__ hstate, const _Float16* __restrict__ wdt,
    float* __restrict__ out)
{
  __shared__ _Float16 d_s[256][56];
  __shared__ float att_s[256];
  __shared__ float sc_s[40];
  __shared__ float wgt[40];

  const int b   = blockIdx.x;
  const int tid = threadIdx.x;
  const int wv  = tid >> 6;
  const int ln  = tid & 63;
  const int l16 = ln & 15;
  const int lq  = ln >> 4;

  att_s[tid] = att[tid];

  int pD2[3];
  #pragma unroll
  for (int nt=0;nt<3;++nt){ int p = 16*nt + l16; pD2[nt] = (p < 40) ? p : 39; }
  const _Float16* hb = hstate + (size_t)b*2*40*256;

  f32x4 dacc[4][3];
  #pragma unroll
  for (int ml=0;ml<4;++ml)
    #pragma unroll
    for (int nt=0;nt<3;++nt){ f32x4 z0; z0[0]=0.f;z0[1]=0.f;z0[2]=0.f;z0[3]=0.f; dacc[ml][nt]=z0; }

  #pragma unroll
  for (int kq = 0; kq < 8; ++kq) {        // k slices of 64: 0..3 fw state, 4..7 bw state
    half8 adA[4], adB[4];
    #pragma unroll
    for (int ml=0;ml<4;++ml) {
      const _Float16* wp = wdt + (size_t)(16*(4*wv+ml)+l16)*512 + 64*kq + 8*lq;
      adA[ml] = *(const half8*)(wp);
      adB[ml] = *(const half8*)(wp + 32);
    }
    #pragma unroll
    for (int kk2=0;kk2<2;++kk2) {
      half8 bD[3];
      #pragma unroll
      for (int nt=0;nt<3;++nt)
        bD[nt] = *(const half8*)(hb + ((size_t)(kq>>2)*40 + pD2[nt])*256
                                    + 64*(kq&3) + 32*kk2 + 8*lq);
      #pragma unroll
      for (int ml=0;ml<4;++ml) {
        half8 a0 = kk2 ? adB[ml] : adA[ml];
        #pragma unroll
        for (int nt=0;nt<3;++nt) dacc[ml][nt] = MFMA16(a0, bD[nt], dacc[ml][nt]);
      }
    }
  }
  #pragma unroll
  for (int ml = 0; ml < 4; ++ml) {
    int d0 = 16*(4*wv+ml) + 4*lq;
    float4 bv = *(const float4*)&bd[d0];
    float bvr[4] = {bv.x, bv.y, bv.z, bv.w};
    #pragma unroll
    for (int nt = 0; nt < 3; ++nt) {
      int p = 16*nt + l16;
      #pragma unroll
      for (int r = 0; r < 4; ++r) {
        float val = tanhn_(dacc[ml][nt][r] + bvr[r]);
        d_s[d0 + r][p] = (_Float16)val;
      }
    }
  }
  __syncthreads();
  // ---------- attention: 10 path-scores per wave, softmax, weighted sum ----------
  #pragma unroll
  for (int q = 0; q < 10; ++q) {
    int pp = 10*wv + q;
    float s = 0.0f;
    #pragma unroll
    for (int j = 0; j < 4; ++j) {
      int d = 64*j + ln;
      s += (float)d_s[d][pp] * att_s[d];
    }
    #pragma unroll
    for (int off = 32; off > 0; off >>= 1) s += __shfl_xor(s, off);
    if (ln == 0) sc_s[pp] = s;
  }
  __syncthreads();
  if (wv == 0) {
    float sc = (ln < 40) ? sc_s[ln] : -1e30f;
    float m = sc;
    #pragma unroll
    for (int off = 32; off > 0; off >>= 1) m = fmaxf(m, __shfl_xor(m, off));
    float e = __expf(sc - m);
    float se = e;
    #pragma unroll
    for (int off = 32; off > 0; off >>= 1) se += __shfl_xor(se, off);
    if (ln < 40) wgt[ln] = e / se;
  }
  __syncthreads();
  {
    float o = 0.0f;
    #pragma unroll 8
    for (int p = 0; p < 40; ++p) o += wgt[p] * (float)d_s[tid][p];
    out[b*256 + tid] = o;
  }
}

extern "C" void kernel_launch(void* const* d_in, const int* in_sizes, int n_in,
                              void* d_out, int out_size, void* d_ws, size_t ws_size,
                              hipStream_t stream)
{
  (void)in_sizes; (void)n_in; (void)out_size;
  const int*   x   = (const int*)  d_in[0];
  const float* emb = (const float*)d_in[1];
  const float* Wk  = (const float*)d_in[2];
  const float* Wr  = (const float*)d_in[3];
  const float* bi  = (const float*)d_in[4];
  const float* Wd  = (const float*)d_in[5];
  const float* bd  = (const float*)d_in[6];
  const float* att = (const float*)d_in[7];
  float* out = (float*)d_out;

  if (ws_size < 52887552u) return;   // need 52.9 MB scratch
  char* ws = (char*)d_ws;
  _Float16* embw   = (_Float16*)(ws + 0);          // [20000][1024] fp16 = 40,960,000 B (fragment-major rows)
  _Float16* wrtb   = (_Float16*)(ws + 40960000);   // fragment-major Wr   =    524,288 B
  _Float16* wkt    = (_Float16*)(ws + 41484288);   // [1024][320]   fp16 =    655,360 B
  _Float16* wdt    = (_Float16*)(ws + 42139648);   // [256][512]    fp16 =    262,144 B
  _Float16* hstate = (_Float16*)(ws + 42401792);   // [256][2][40][256] fp16 = 10,485,760 B

  k0_prep<<<dim3(1280), dim3(256), 0, stream>>>(Wk, Wr, Wd, wkt, wrtb, wdt);
  k1_embw<<<dim3(313), dim3(512), 0, stream>>>(emb, bi, wkt, embw);
  k2_rnn <<<dim3(512), dim3(256), 0, stream>>>(x, embw, wrtb, hstate);
  k3_head<<<dim3(256), dim3(256), 0, stream>>>(bd, att, hstate, wdt, out);
}

// Round 15
// 460.206 us; speedup vs baseline: 1.3499x; 1.1059x over previous
//
#include <hip/hip_runtime.h>

using half8  = __attribute__((ext_vector_type(8))) _Float16;
using half4v = __attribute__((ext_vector_type(4))) _Float16;
using f32x4  = __attribute__((ext_vector_type(4))) float;

#define MFMA16(a,b,c) __builtin_amdgcn_mfma_f32_16x16x32_f16((a),(b),(c),0,0,0)
#define LOG2E 1.4426950408889634f
#define KTC  -2.8853900817779268f   /* -2*log2(e): tanh(c) = 2/(1+2^(c*KTC)) - 1 */

__device__ __forceinline__ float sigp_(float zp){           // sigmoid, zp pre-scaled by log2e
  return __builtin_amdgcn_rcpf(1.0f + exp2f(-zp));
}
__device__ __forceinline__ float tanhp_(float zp){          // tanh, zp pre-scaled by log2e
  return fmaf(2.0f, __builtin_amdgcn_rcpf(1.0f + exp2f(-2.0f*zp)), -1.0f);
}
__device__ __forceinline__ float tanhn_(float x){           // tanh, natural units
  return fmaf(2.0f, __builtin_amdgcn_rcpf(1.0f + exp2f(x*KTC)), -1.0f);
}

// ---------------- K0: weight transposes / fp16 packing ----------------
// wrtb FRAGMENT-MAJOR: [jt][kq][g][kk2][hq][lane 0..63][8 fp16]: wave A-fragment load
// = 64 lanes x 16B fully contiguous (1KB streams). Values = Wr[k][G]*log2e with
// k = kq*64+kk2*32+(ln>>4)*8+b, G = g*256+jt*64+hq*16+(ln&15).
__global__ void k0_prep(const float* __restrict__ Wk, const float* __restrict__ Wr,
                        const float* __restrict__ Wd, _Float16* __restrict__ wkt,
                        _Float16* __restrict__ wrtb, _Float16* __restrict__ wdt)
{
  int i = blockIdx.x * 256 + threadIdx.x;
  if (i < 1024*320) {
    int g = i / 320, k = i - g*320;
    wkt[i] = (_Float16)((k < 300) ? Wk[k*1024 + g]*LOG2E : 0.0f);
  }
  if (i < 4*256*256) {
    int b   = i & 7;
    int ln2 = (i >> 3) & 63;
    int hq2 = (i >> 9) & 3;
    int kk2 = (i >> 11) & 1;
    int g   = (i >> 12) & 3;
    int kq  = (i >> 14) & 3;
    int jt  = (i >> 16) & 3;
    int k = kq*64 + kk2*32 + (ln2 >> 4)*8 + b;
    int G = g*256 + jt*64 + hq2*16 + (ln2 & 15);
    wrtb[i] = (_Float16)(Wr[k*1024 + G]*LOG2E);
  }
  if (i < 256*512) {
    int d = i >> 9, k = i & 511;
    wdt[i] = (_Float16)Wd[k*256 + d];
  }
}

// ---------------- K1: embW = (emb @ Wk + b)*log2e ----------------
// embw per-row fragment-major: [v][jt][hq][lq][g][4] -> one lane's acc-init for all
// 4 gates at its (hq,lq) is 32B contiguous.
__global__ __launch_bounds__(512, 2) void k1_embw(
    const float* __restrict__ emb, const float* __restrict__ bias,
    const _Float16* __restrict__ wkt, _Float16* __restrict__ embw)
{
  __shared__ _Float16 a_s[1024][40];
  __shared__ _Float16 e_s[64][40];
  const int tid = threadIdx.x;
  const int wv = tid >> 6, ln = tid & 63, l16 = ln & 15, lq = ln >> 4;
  const int v0 = blockIdx.x * 64;

  f32x4 acc[8][4];
  #pragma unroll
  for (int ml=0;ml<8;++ml)
    #pragma unroll
    for (int nt=0;nt<4;++nt){ f32x4 z0; z0[0]=0.f;z0[1]=0.f;z0[2]=0.f;z0[3]=0.f; acc[ml][nt]=z0; }

  const int evv = tid >> 2;
  const int ekq = tid & 3;

  for (int c = 0; c < 10; ++c) {
    {
      const uint4* sp  = (const uint4*)(wkt + (size_t)(2*tid)*320 + 32*c);
      uint4 r0=sp[0], r1=sp[1], r2=sp[2], r3=sp[3];
      const uint4* sp2 = (const uint4*)(wkt + (size_t)(2*tid+1)*320 + 32*c);
      uint4 r4=sp2[0], r5=sp2[1], r6=sp2[2], r7=sp2[3];
      uint4* dq  = (uint4*)&a_s[2*tid][0];
      dq[0]=r0; dq[1]=r1; dq[2]=r2; dq[3]=r3;
      uint4* dq2 = (uint4*)&a_s[2*tid+1][0];
      dq2[0]=r4; dq2[1]=r5; dq2[2]=r6; dq2[3]=r7;
    }
    if (tid < 256) {
      int vsrc = v0 + evv; if (vsrc > 19999) vsrc = 19999;
      float f0,f1,f2,f3,f4,f5,f6,f7;
      if (c < 9) {
        const float4* sp = (const float4*)(emb + (size_t)vsrc*300 + 32*c + 8*ekq);
        float4 fa = sp[0], fb = sp[1];
        f0=fa.x; f1=fa.y; f2=fa.z; f3=fa.w; f4=fb.x; f5=fb.y; f6=fb.z; f7=fb.w;
      } else {
        const float* sp = emb + (size_t)vsrc*300;
        int k0 = 288 + 8*ekq;
        f0 = (k0+0<300)? sp[k0+0] : 0.f;  f1 = (k0+1<300)? sp[k0+1] : 0.f;
        f2 = (k0+2<300)? sp[k0+2] : 0.f;  f3 = (k0+3<300)? sp[k0+3] : 0.f;
        f4 = (k0+4<300)? sp[k0+4] : 0.f;  f5 = (k0+5<300)? sp[k0+5] : 0.f;
        f6 = (k0+6<300)? sp[k0+6] : 0.f;  f7 = (k0+7<300)? sp[k0+7] : 0.f;
      }
      half8 hv;
      hv[0]=(_Float16)f0; hv[1]=(_Float16)f1; hv[2]=(_Float16)f2; hv[3]=(_Float16)f3;
      hv[4]=(_Float16)f4; hv[5]=(_Float16)f5; hv[6]=(_Float16)f6; hv[7]=(_Float16)f7;
      *(half8*)&e_s[evv][8*ekq] = hv;
    }
    __syncthreads();
    half8 bf[4];
    #pragma unroll
    for (int nt=0;nt<4;++nt) bf[nt] = *(const half8*)&e_s[16*nt + l16][8*lq];
    #pragma unroll
    for (int ml=0;ml<8;++ml) {
      half8 af = *(const half8*)&a_s[16*(8*wv+ml) + l16][8*lq];
      #pragma unroll
      for (int nt=0;nt<4;++nt) acc[ml][nt] = MFMA16(af, bf[nt], acc[ml][nt]);
    }
    __syncthreads();
  }
  #pragma unroll
  for (int ml=0;ml<8;++ml) {
    int g0 = 16*(8*wv+ml) + 4*lq;
    float4 bv = *(const float4*)&bias[g0];
    float bvr[4] = {bv.x*LOG2E, bv.y*LOG2E, bv.z*LOG2E, bv.w*LOG2E};
    int jt  = (g0 >> 6) & 3;
    int coff = ((g0 >> 4) & 3)*64 + ((g0 >> 2) & 3)*16 + (g0 >> 8)*4;  // hq*64+lq*16+gate*4
    #pragma unroll
    for (int nt=0;nt<4;++nt) {
      int v = v0 + 16*nt + l16;
      if (v < 20000) {
        half4v hv;
        hv[0]=(_Float16)(acc[ml][nt][0]+bvr[0]);
        hv[1]=(_Float16)(acc[ml][nt][1]+bvr[1]);
        hv[2]=(_Float16)(acc[ml][nt][2]+bvr[2]);
        hv[3]=(_Float16)(acc[ml][nt][3]+bvr[3]);
        *(half4v*)&embw[(size_t)v*1024 + 256*jt + coff] = hv;
      }
    }
  }
}

// ---------------- K2: bi-LSTM recurrence, 1 block = (card, direction) ----------------
// R15 (vs R14): drop the eR double-buffer (R13 proved the extra prefetch lead is
// worthless) -> single eR, R12-style consume-then-prefetch (still ~1Kcyc lead).
// Saves 24 regs: per-wave unified VGPR+AGPR total ~212 < 256 -> TWO waves/SIMD at
// (256,1) with zero spill and no 128-arch pinning (R12's trap). At 1 wave/SIMD the
// measured issue util was VALU 37% + MFMA 14%; a second co-resident (independent,
// barrier-free) block fills the ~50% latency gaps, and all 512 blocks run in ONE
// round instead of two. Tell: OccupancyPercent ~23.5% good, ~11.8% = still over 256.

#define ISSUE_E(JT, TT) do { \
    _Pragma("unroll") for (int nt=0;nt<3;++nt) { \
      int idx_ = x_lds[pA12[nt] + (TT)]; \
      const _Float16* ep = embw + (size_t)idx_*1024 + (JT)*256 + ebase; \
      eR[0][nt] = *(const half8*)(ep); \
      eR[1][nt] = *(const half8*)(ep + 8); \
    } } while(0)

#define ACC_FROM_E() do { \
    _Pragma("unroll") for (int g=0;g<4;++g) \
      _Pragma("unroll") for (int nt=0;nt<3;++nt) { \
        f32x4 a0; \
        a0[0]=(float)eR[g>>1][nt][(g&1)*4+0]; a0[1]=(float)eR[g>>1][nt][(g&1)*4+1]; \
        a0[2]=(float)eR[g>>1][nt][(g&1)*4+2]; a0[3]=(float)eR[g>>1][nt][(g&1)*4+3]; \
        acc[g][nt]=a0; \
      } } while(0)

#define ISSUE_A(BUF,JT,KQ) do { \
    const _Float16* ap = wrtb + (size_t)((JT)*4+(KQ))*16384 + abase; \
    _Pragma("unroll") for (int g=0;g<4;++g) { \
      BUF[2*g+0] = *(const half8*)(ap + (2*g+0)*2048); \
      BUF[2*g+1] = *(const half8*)(ap + (2*g+1)*2048); \
    } } while(0)

#define MFMAQ(BUF,KQ) do { \
    _Pragma("unroll") for (int kk2=0;kk2<2;++kk2) { \
      half8 bF[3]; \
      _Pragma("unroll") for (int nt=0;nt<3;++nt) \
        bF[nt] = *(const half8*)(hc + bbase[nt] + ((64*(KQ)+32*kk2+8*lq) ^ bswz[nt])); \
      _Pragma("unroll") for (int g=0;g<4;++g) \
        _Pragma("unroll") for (int nt=0;nt<3;++nt) \
          acc[g][nt] = MFMA16(BUF[2*g+kk2], bF[nt], acc[g][nt]); \
    } } while(0)

#define GATES_J(JT, CR) do { \
    _Pragma("unroll") for (int nt=0;nt<3;++nt) { \
      f32x4 cn_; half4v hv; \
      _Pragma("unroll") for (int r=0;r<4;++r) { \
        float zi=acc[0][nt][r], zf=acc[1][nt][r], zg=acc[2][nt][r], zo=acc[3][nt][r]; \
        float cn = fmaf(sigp_(zf), CR[nt][r], sigp_(zi)*tanhp_(zg)); \
        cn_[r]=cn; hv[r]=(_Float16)(sigp_(zo)*tanhn_(cn)); \
      } \
      CR[nt] = cn_; \
      *(half4v*)(hn + bbase[nt] + ((64*(JT)+16*hq+4*lq) ^ bswz[nt])) = hv; \
    } } while(0)

#define GATES0_J(JT, CR) do { \
    _Pragma("unroll") for (int nt=0;nt<3;++nt) { \
      f32x4 cn_; half4v hv; \
      _Pragma("unroll") for (int r=0;r<4;++r) { \
        float zi=acc[0][nt][r], zg=acc[2][nt][r], zo=acc[3][nt][r]; \
        float cn = sigp_(zi)*tanhp_(zg); \
        cn_[r]=cn; hv[r]=(_Float16)(sigp_(zo)*tanhn_(cn)); \
      } \
      CR[nt] = cn_; \
      *(half4v*)(hn + bbase[nt] + ((64*(JT)+16*hq+4*lq) ^ bswz[nt])) = hv; \
    } } while(0)

__global__ __launch_bounds__(256, 1) void k2_rnn(
    const int* __restrict__ x, const _Float16* __restrict__ embw,
    const _Float16* __restrict__ wrtb, _Float16* __restrict__ hstate)
{
  __shared__ _Float16 h_s[2][48][256];   // 48 KB
  __shared__ int x_lds[480];             // token table for this card (1.9 KB)

  const int bid = blockIdx.x;
  const int b   = bid & 255;             // card
  const int dir = bid >> 8;              // 0 = fw, 1 = bw (block-uniform)
  const int tid = threadIdx.x;
  const int wv  = tid >> 6;
  const int ln  = tid & 63;
  const int l16 = ln & 15;
  const int lq  = ln >> 4;
  const int hq  = wv;                    // 16-col subtile in each 64-col gate chunk

  const int dtt0 = dir ? 11 : 0;
  const int dsgn = dir ? -1 : 1;
  const int xb   = b*480;

  if (tid < 240) {                       // stage token table to LDS
    *(int2*)&x_lds[2*tid] = *(const int2*)(x + xb + 2*tid);
  }

  int pA12[3], bbase[3], bswz[3];
  #pragma unroll
  for (int nt=0;nt<3;++nt) {
    int s = 16*nt + l16;                 // seq row 0..47 (40..47 dup path 39)
    pA12[nt] = ((s < 40) ? s : 39) * 12;
    bbase[nt] = s*256; bswz[nt] = (s&7)<<3;
  }
  const int ebase = hq*64 + lq*16;       // fragment-major embw offset within [v][jt]
  const size_t abase = (size_t)hq*512 + ln*8;  // fragment-major wrtb: lane-contiguous

  half8  eR[2][3];                       // single-buffered gather (R12 pattern)
  half8  aRa[8], aRb[8];
  f32x4  acc[4][3];
  f32x4  cA[3], cB[3], cC[3], cD[3];     // cell state, statically-named per jt chunk

  __syncthreads();                       // x_lds ready

  // ---- t = 0: z = xg (h=0, no MFMA; c starts at 0) ----
  {
    _Float16* hn = &h_s[1][0][0];
    ISSUE_E(0, dtt0);
    ACC_FROM_E(); ISSUE_E(1, dtt0);        GATES0_J(0, cA);
    ACC_FROM_E(); ISSUE_E(2, dtt0);        GATES0_J(1, cB);
    ACC_FROM_E(); ISSUE_E(3, dtt0);        GATES0_J(2, cC);
    ACC_FROM_E(); ISSUE_E(0, dtt0 + dsgn); GATES0_J(3, cD);
  }

  // ---- t = 1..11: 4 jt chunks/step; consume-then-prefetch single eR ----
  #pragma unroll 1
  for (int t = 1; t < 12; ++t) {
    __syncthreads();                     // h[t&1] committed by all waves
    const _Float16* hc = &h_s[t&1][0][0];
    _Float16*       hn = &h_s[(t+1)&1][0][0];
    const bool last = (t == 11);
    const int ttc = dtt0 + dsgn*t;
    #pragma unroll 1
    for (int jt = 0; jt < 4; ++jt) {
      ISSUE_A(aRa, jt, 0);
      ISSUE_A(aRb, jt, 1);
      ACC_FROM_E();                      // consume chunk jt (prefetched last body)
      if (jt < 3)      { ISSUE_E(jt+1, ttc); }
      else if (!last)  { ISSUE_E(0, ttc + dsgn); }
      MFMAQ(aRa, 0); ISSUE_A(aRa, jt, 2);
      MFMAQ(aRb, 1); ISSUE_A(aRb, jt, 3);
      MFMAQ(aRa, 2);
      MFMAQ(aRb, 3);
      if      (jt == 0) { GATES_J(0, cA); }
      else if (jt == 1) { GATES_J(1, cB); }
      else if (jt == 2) { GATES_J(2, cC); }
      else              { GATES_J(3, cD); }
    }
  }
  __syncthreads();                       // final state (h_s[0]) committed

  // ---- export final h (unswizzled) to hstate[b][dir][40][256] ----
  #pragma unroll
  for (int pass = 0; pass < 5; ++pass) {
    int row = 8*pass + (tid >> 5);
    int c0  = (tid & 31) * 8;
    half8 v = *(const half8*)&h_s[0][row][c0 ^ ((row & 7) << 3)];
    *(half8*)&hstate[(((size_t)b*2 + dir)*40 + row)*256 + c0] = v;
  }
}

// ---------------- K3: dense + attention head, 1 block = 1 card ----------------
__global__ __launch_bounds__(256) void k3_head(
    const float* __restrict__ bd, const float* __restrict__ att,
    const _Float16* __restrict__ hstate, const _Float16* __restrict__ wdt,
    float* __restrict__ out)
{
  __shared__ _Float16 d_s[256][56];
  __shared__ float att_s[256];
  __shared__ float sc_s[40];
  __shared__ float wgt[40];

  const int b   = blockIdx.x;
  const int tid = threadIdx.x;
  const int wv  = tid >> 6;
  const int ln  = tid & 63;
  const int l16 = ln & 15;
  const int lq  = ln >> 4;

  att_s[tid] = att[tid];

  int pD2[3];
  #pragma unroll
  for (int nt=0;nt<3;++nt){ int p = 16*nt + l16; pD2[nt] = (p < 40) ? p : 39; }
  const _Float16* hb = hstate + (size_t)b*2*40*256;

  f32x4 dacc[4][3];
  #pragma unroll
  for (int ml=0;ml<4;++ml)
    #pragma unroll
    for (int nt=0;nt<3;++nt){ f32x4 z0; z0[0]=0.f;z0[1]=0.f;z0[2]=0.f;z0[3]=0.f; dacc[ml][nt]=z0; }

  #pragma unroll
  for (int kq = 0; kq < 8; ++kq) {        // k slices of 64: 0..3 fw state, 4..7 bw state
    half8 adA[4], adB[4];
    #pragma unroll
    for (int ml=0;ml<4;++ml) {
      const _Float16* wp = wdt + (size_t)(16*(4*wv+ml)+l16)*512 + 64*kq + 8*lq;
      adA[ml] = *(const half8*)(wp);
      adB[ml] = *(const half8*)(wp + 32);
    }
    #pragma unroll
    for (int kk2=0;kk2<2;++kk2) {
      half8 bD[3];
      #pragma unroll
      for (int nt=0;nt<3;++nt)
        bD[nt] = *(const half8*)(hb + ((size_t)(kq>>2)*40 + pD2[nt])*256
                                    + 64*(kq&3) + 32*kk2 + 8*lq);
      #pragma unroll
      for (int ml=0;ml<4;++ml) {
        half8 a0 = kk2 ? adB[ml] : adA[ml];
        #pragma unroll
        for (int nt=0;nt<3;++nt) dacc[ml][nt] = MFMA16(a0, bD[nt], dacc[ml][nt]);
      }
    }
  }
  #pragma unroll
  for (int ml = 0; ml < 4; ++ml) {
    int d0 = 16*(4*wv+ml) + 4*lq;
    float4 bv = *(const float4*)&bd[d0];
    float bvr[4] = {bv.x, bv.y, bv.z, bv.w};
    #pragma unroll
    for (int nt = 0; nt < 3; ++nt) {
      int p = 16*nt + l16;
      #pragma unroll
      for (int r = 0; r < 4; ++r) {
        float val = tanhn_(dacc[ml][nt][r] + bvr[r]);
        d_s[d0 + r][p] = (_Float16)val;
      }
    }
  }
  __syncthreads();
  // ---------- attention: 10 path-scores per wave, softmax, weighted sum ----------
  #pragma unroll
  for (int q = 0; q < 10; ++q) {
    int pp = 10*wv + q;
    float s = 0.0f;
    #pragma unroll
    for (int j = 0; j < 4; ++j) {
      int d = 64*j + ln;
      s += (float)d_s[d][pp] * att_s[d];
    }
    #pragma unroll
    for (int off = 32; off > 0; off >>= 1) s += __shfl_xor(s, off);
    if (ln == 0) sc_s[pp] = s;
  }
  __syncthreads();
  if (wv == 0) {
    float sc = (ln < 40) ? sc_s[ln] : -1e30f;
    float m = sc;
    #pragma unroll
    for (int off = 32; off > 0; off >>= 1) m = fmaxf(m, __shfl_xor(m, off));
    float e = __expf(sc - m);
    float se = e;
    #pragma unroll
    for (int off = 32; off > 0; off >>= 1) se += __shfl_xor(se, off);
    if (ln < 40) wgt[ln] = e / se;
  }
  __syncthreads();
  {
    float o = 0.0f;
    #pragma unroll 8
    for (int p = 0; p < 40; ++p) o += wgt[p] * (float)d_s[tid][p];
    out[b*256 + tid] = o;
  }
}

extern "C" void kernel_launch(void* const* d_in, const int* in_sizes, int n_in,
                              void* d_out, int out_size, void* d_ws, size_t ws_size,
                              hipStream_t stream)
{
  (void)in_sizes; (void)n_in; (void)out_size;
  const int*   x   = (const int*)  d_in[0];
  const float* emb = (const float*)d_in[1];
  const float* Wk  = (const float*)d_in[2];
  const float* Wr  = (const float*)d_in[3];
  const float* bi  = (const float*)d_in[4];
  const float* Wd  = (const float*)d_in[5];
  const float* bd  = (const float*)d_in[6];
  const float* att = (const float*)d_in[7];
  float* out = (float*)d_out;

  if (ws_size < 52887552u) return;   // need 52.9 MB scratch
  char* ws = (char*)d_ws;
  _Float16* embw   = (_Float16*)(ws + 0);          // [20000][1024] fp16 = 40,960,000 B (fragment-major rows)
  _Float16* wrtb   = (_Float16*)(ws + 40960000);   // fragment-major Wr   =    524,288 B
  _Float16* wkt    = (_Float16*)(ws + 41484288);   // [1024][320]   fp16 =    655,360 B
  _Float16* wdt    = (_Float16*)(ws + 42139648);   // [256][512]    fp16 =    262,144 B
  _Float16* hstate = (_Float16*)(ws + 42401792);   // [256][2][40][256] fp16 = 10,485,760 B

  k0_prep<<<dim3(1280), dim3(256), 0, stream>>>(Wk, Wr, Wd, wkt, wrtb, wdt);
  k1_embw<<<dim3(313), dim3(512), 0, stream>>>(emb, bi, wkt, embw);
  k2_rnn <<<dim3(512), dim3(256), 0, stream>>>(x, embw, wrtb, hstate);
  k3_head<<<dim3(256), dim3(256), 0, stream>>>(bd, att, hstate, wdt, out);
}